// Round 11
// baseline (1619.760 us; speedup 1.0000x reference)
//
#include <hip/hip_runtime.h>

// ============================================================================
// Fully-connected e3nn-style tensor product, IRREPS = 32x0e + 32x1o + 32x2e
// BATCH=8192, FEAT=288, 11 uvw paths, weights flat [360448].
//
// R1 (lane=z, NW=16): 542us, VALU 35%, occ 26%. FETCH=compulsory.
// R2 (global transpose): 1280us, VALU 14% -> REVERTED (killed L1 locality).
// R3 (NW=32, half grid): 837us, VALU 13%, occ 12% -> REVERTED.
//   Lesson: per-wave VALU issue ~constant vs wave count -> LATENCY-bound on
//   SGPR-serialized s_load weight rows (max 2-3 in flight, ~240cy each).
// R4 (16z x 4 w-octet lanes, per-lane float4 weight loads): FAILED 3.32 —
//   transcription bug: path (2,0,2) template D2=5, must be D2=1 (x2 is l0).
//   All other 10 call sites verified against R1's known-good params.
// R5: fix that one template arg; design otherwise identical to R4.
//   (R10 slot: infra error, never ran — resubmitted unchanged.)
// ============================================================================

__device__ float g_w3[11 * 128];

// ---------------- Wigner 3j setup --------------------------------------------

__device__ __forceinline__ double dfact(int n) {
    double r = 1.0;
    for (int i = 2; i <= n; ++i) r *= (double)i;
    return r;
}

__device__ double cg_coef(int j1, int m1, int j2, int m2, int j3, int m3) {
    if (m1 + m2 != m3) return 0.0;
    int lo = (j1 > j2) ? (j1 - j2) : (j2 - j1);
    if (j3 > j1 + j2 || j3 < lo) return 0.0;
    double pre = (2.0 * j3 + 1.0) * dfact(j3 + j1 - j2) * dfact(j3 - j1 + j2) *
                 dfact(j1 + j2 - j3) / dfact(j1 + j2 + j3 + 1);
    pre *= dfact(j3 + m3) * dfact(j3 - m3) * dfact(j1 - m1) * dfact(j1 + m1) *
           dfact(j2 - m2) * dfact(j2 + m2);
    double s = 0.0;
    for (int k = 0; k <= j1 + j2 - j3; ++k) {
        int a1 = j1 + j2 - j3 - k, a2 = j1 - m1 - k, a3 = j2 + m2 - k;
        int a4 = j3 - j2 + m1 + k, a5 = j3 - j1 - m2 + k;
        if (a1 < 0 || a2 < 0 || a3 < 0 || a4 < 0 || a5 < 0) continue;
        double t = 1.0 / (dfact(k) * dfact(a1) * dfact(a2) * dfact(a3) * dfact(a4) * dfact(a5));
        s += (k & 1) ? -t : t;
    }
    return sqrt(pre) * s;
}

// Q[a][mi] for real-SH basis change (scratch-free, matches reference _q)
__device__ __forceinline__ void qval(int l, int a, int mi, double& re, double& im) {
    re = 0.0; im = 0.0;
    const double inv = 0.7071067811865475244;
    int ma = a - l, mc = mi - l;
    if (ma == 0) { if (mc == 0) re = 1.0; return; }
    if (ma > 0) {
        if (mc == ma)        re = (ma & 1) ? -inv : inv;
        else if (mc == -ma)  re = inv;
    } else {
        int mm = -ma;
        if (mc == ma)        im = inv;
        else if (mc == -ma)  im = -((mm & 1) ? -inv : inv);
    }
}

__global__ void wigner3j_setup() {
    const int L1[11] = {0,0,0,1,1,1,1,2,2,2,2};
    const int L2[11] = {0,1,2,0,1,1,2,0,1,2,2};
    const int L3[11] = {0,1,2,1,0,2,1,2,1,0,2};
    const int p = blockIdx.x;
    const int l1 = L1[p], l2 = L2[p], l3 = L3[p];
    const int d1 = 2 * l1 + 1, d2 = 2 * l2 + 1, d3 = 2 * l3 + 1;
    const int n = d1 * d2 * d3;

    __shared__ double sre[125], sim[125];
    __shared__ double s_scale;
    __shared__ int s_im;

    const int e = threadIdx.x;
    if (e < n) {
        int a = e / (d2 * d3);
        int r = e - a * d2 * d3;
        int b = r / d3;
        int c = r - b * d3;
        double tre = 0.0, tim = 0.0;
        for (int m1 = -l1; m1 <= l1; ++m1) {
            for (int m2 = -l2; m2 <= l2; ++m2) {
                int m3 = -(m1 + m2);
                if (m3 < -l3 || m3 > l3) continue;
                int ex = l1 - l2 - m3;
                double sgn = (ex % 2 != 0) ? -1.0 : 1.0;
                double C = sgn * cg_coef(l1, m1, l2, m2, l3, -m3);
                if (C == 0.0) continue;
                double r1, i1, r2, i2, r3, i3;
                qval(l1, a, m1 + l1, r1, i1);
                qval(l2, b, m2 + l2, r2, i2);
                qval(l3, c, m3 + l3, r3, i3);
                i1 = -i1; i2 = -i2; i3 = -i3;  // conj
                double rr = r1 * r2 - i1 * i2;
                double ri = r1 * i2 + i1 * r2;
                double fr = rr * r3 - ri * i3;
                double fi = rr * i3 + ri * r3;
                tre += C * fr;
                tim += C * fi;
            }
        }
        sre[e] = tre; sim[e] = tim;
    }
    __syncthreads();
    if (threadIdx.x == 0) {
        double sar = 0.0, sai = 0.0;
        for (int i = 0; i < n; ++i) { sar += fabs(sre[i]); sai += fabs(sim[i]); }
        int useim = (sar >= sai) ? 0 : 1;
        double ss = 0.0;
        for (int i = 0; i < n; ++i) { double v = useim ? sim[i] : sre[i]; ss += v * v; }
        s_scale = 1.0 / sqrt(ss);
        s_im = useim;
    }
    __syncthreads();
    if (e < n) {
        double v = s_im ? sim[e] : sre[e];
        g_w3[p * 128 + e] = (float)(v * s_scale);
    }
}

// ---------------- Main tensor-product kernel ---------------------------------
//
// Lane = (z within 16-row tile, w-octet). do_path: held side H in VGPRs
// (chunked), streamed side per s, CG via c[i] precompute, weights as
// per-lane float4x2 VGPR loads (vmcnt-pipelined), acc[8] per lane.
// Wp passed pre-offset by wq*8.  D2 = dim of the x2 irrep (w3 row stride).

template <int DH, int DS, int D2, int DO, bool HX1>
__device__ __forceinline__ void do_path(const float* __restrict__ xh,
                                        const float* __restrict__ xs,
                                        const float* __restrict__ Wp,
                                        const float* __restrict__ w3p,
                                        int k, float* __restrict__ acc) {
    // w3 slice for this k: w3l[held][stream]
    float w3l[DH][DS];
#pragma unroll
    for (int ih = 0; ih < DH; ++ih) {
#pragma unroll
        for (int is = 0; is < DS; ++is) {
            const int i = HX1 ? ih : is;  // x1 component
            const int j = HX1 ? is : ih;  // x2 component
            w3l[ih][is] = w3p[(i * D2 + j) * DO + k];
        }
    }
    constexpr int CH = (DH >= 5) ? 8 : (DH >= 3 ? 16 : 32);  // VGPR cap
#pragma unroll 1
    for (int h0 = 0; h0 < 32; h0 += CH) {
        float H[CH * DH];
#pragma unroll
        for (int h = 0; h < CH; ++h) {
#pragma unroll
            for (int i = 0; i < DH; ++i) H[h * DH + i] = xh[(h0 + h) * DH + i];
        }
#pragma unroll 2
        for (int s = 0; s < 32; ++s) {
            float b[DS];
#pragma unroll
            for (int j = 0; j < DS; ++j) b[j] = xs[s * DS + j];
            float c[DH];
#pragma unroll
            for (int i = 0; i < DH; ++i) {
                float t = 0.f;
#pragma unroll
                for (int j = 0; j < DS; ++j) t = fmaf(w3l[i][j], b[j], t);
                c[i] = t;
            }
#pragma unroll
            for (int h = 0; h < CH; ++h) {
                float o = 0.f;
#pragma unroll
                for (int i = 0; i < DH; ++i) o = fmaf(c[i], H[h * DH + i], o);
                const float* wrow = Wp + (HX1 ? (h0 + h) * 1024 + s * 32
                                              : s * 1024 + (h0 + h) * 32);
                const float4 wa = *reinterpret_cast<const float4*>(wrow);
                const float4 wb = *reinterpret_cast<const float4*>(wrow + 4);
                acc[0] = fmaf(wa.x, o, acc[0]);
                acc[1] = fmaf(wa.y, o, acc[1]);
                acc[2] = fmaf(wa.z, o, acc[2]);
                acc[3] = fmaf(wa.w, o, acc[3]);
                acc[4] = fmaf(wb.x, o, acc[4]);
                acc[5] = fmaf(wb.y, o, acc[5]);
                acc[6] = fmaf(wb.z, o, acc[6]);
                acc[7] = fmaf(wb.w, o, acc[7]);
            }
        }
    }
}

__global__ __launch_bounds__(64, 4) void tp_main(const float* __restrict__ x1,
                                                 const float* __restrict__ x2,
                                                 const float* __restrict__ W,
                                                 float* __restrict__ out) {
    const int lane = threadIdx.x;
    const int zl = lane & 15;
    const int wq = lane >> 4;                  // w-octet 0..3
    const int z = blockIdx.x * 16 + zl;
    const float* r1 = x1 + (size_t)z * 288;
    const float* r2 = x2 + (size_t)z * 288;
    const float* w3t = g_w3;
    const int wo = wq * 8;                     // weight column offset

    float acc[8];
#pragma unroll
    for (int i = 0; i < 8; ++i) acc[i] = 0.f;

    const int arm = blockIdx.y;
    int io, k;
    if (arm == 0)      { io = 0; k = 0; }
    else if (arm <= 3) { io = 1; k = arm - 1; }
    else               { io = 2; k = arm - 4; }

    if (io == 0) {
        // (0,0,0): hold x2(l0), stream x1(l0)
        do_path<1, 1, 1, 1, false>(r2 + 0,   r1 + 0,   W + 0 * 32768 + wo,  w3t + 0 * 128, 0, acc);
        // (1,1,0): hold x2(l1), stream x1(l1)
        do_path<3, 3, 3, 1, false>(r2 + 32,  r1 + 32,  W + 4 * 32768 + wo,  w3t + 4 * 128, 0, acc);
        // (2,2,0): hold x2(l2), stream x1(l2)
        do_path<5, 5, 5, 1, false>(r2 + 128, r1 + 128, W + 9 * 32768 + wo,  w3t + 9 * 128, 0, acc);
    } else if (io == 1) {
        // (0,1,1): hold x1(l0), stream x2(l1)
        do_path<1, 3, 3, 3, true >(r1 + 0,   r2 + 32,  W + 1 * 32768 + wo,  w3t + 1 * 128, k, acc);
        // (1,0,1): hold x2(l0), stream x1(l1)
        do_path<1, 3, 1, 3, false>(r2 + 0,   r1 + 32,  W + 3 * 32768 + wo,  w3t + 3 * 128, k, acc);
        // (1,2,1): hold x1(l1), stream x2(l2)
        do_path<3, 5, 5, 3, true >(r1 + 32,  r2 + 128, W + 6 * 32768 + wo,  w3t + 6 * 128, k, acc);
        // (2,1,1): hold x2(l1), stream x1(l2)
        do_path<3, 5, 3, 3, false>(r2 + 32,  r1 + 128, W + 8 * 32768 + wo,  w3t + 8 * 128, k, acc);
    } else {
        // (0,2,2): hold x1(l0), stream x2(l2)
        do_path<1, 5, 5, 5, true >(r1 + 0,   r2 + 128, W + 2 * 32768 + wo,  w3t + 2 * 128, k, acc);
        // (1,1,2): hold x2(l1), stream x1(l1)
        do_path<3, 3, 3, 5, false>(r2 + 32,  r1 + 32,  W + 5 * 32768 + wo,  w3t + 5 * 128, k, acc);
        // (2,0,2): hold x2(l0), stream x1(l2)  [D2=1: x2 is l0 — R4 bugfix]
        do_path<1, 5, 1, 5, false>(r2 + 0,   r1 + 128, W + 7 * 32768 + wo,  w3t + 7 * 128, k, acc);
        // (2,2,2): hold x2(l2), stream x1(l2)
        do_path<5, 5, 5, 5, false>(r2 + 128, r1 + 128, W + 10 * 32768 + wo, w3t + 10 * 128, k, acc);
    }

    // epilogue: alpha = sqrt((2lo+1)/fan_in)
    const float alpha = (io == 0) ? 0.018042196f : ((io == 1) ? 0.027063294f : 0.034938562f);
    const int off_o   = (io == 0) ? 0 : ((io == 1) ? 32 : 128);
    const int DOd     = (io == 0) ? 1 : ((io == 1) ? 3 : 5);
    float* orow = out + (size_t)z * 288 + off_o + k;
#pragma unroll
    for (int j = 0; j < 8; ++j) orow[(wo + j) * DOd] = alpha * acc[j];
}

// ---------------- launch -----------------------------------------------------

extern "C" void kernel_launch(void* const* d_in, const int* in_sizes, int n_in,
                              void* d_out, int out_size, void* d_ws, size_t ws_size,
                              hipStream_t stream) {
    const float* x1 = (const float*)d_in[0];
    const float* x2 = (const float*)d_in[1];
    const float* W  = (const float*)d_in[2];
    float* out = (float*)d_out;

    wigner3j_setup<<<dim3(11), dim3(128), 0, stream>>>();
    tp_main<<<dim3(512, 9), dim3(64), 0, stream>>>(x1, x2, W, out);
}

// Round 12
// 1290.292 us; speedup vs baseline: 1.2553x; 1.2553x over previous
//
#include <hip/hip_runtime.h>

// ============================================================================
// Fully-connected e3nn-style tensor product, IRREPS = 32x0e + 32x1o + 32x2e
// BATCH=8192, FEAT=288, 11 uvw paths, weights flat [360448].
//
// R1 (lane=z, NW=16): 542us, VALU 35%, occ 26%. FETCH=compulsory 21MB.
// R2 (global transpose): 1280us -> REVERTED (killed L1 locality).
// R3 (NW=32, half grid): 837us -> REVERTED (latency-bound per wave).
// R4 (16z x 4 w-octets, per-lane float4 weight loads): FAILED (one bad
//   template arg: (2,0,2) D2 must be 1).
// R5 (bugfix): PASSED 1620us BUT CONFOUNDED: launch_bounds(64,4) capped
//   VGPR at 64 < ~100 needed -> scratch spill (FETCH 61MB, WRITE 88MB vs
//   9.4MB output = spill traffic; VALU 15%).
// R6: __launch_bounds__(64,2) -> cap 256 VGPR, no spill. Clean test of the
//   R4 theory. Predict FETCH ~22MB, WRITE ~9.2MB, 200-300us.
// ============================================================================

__device__ float g_w3[11 * 128];

// ---------------- Wigner 3j setup --------------------------------------------

__device__ __forceinline__ double dfact(int n) {
    double r = 1.0;
    for (int i = 2; i <= n; ++i) r *= (double)i;
    return r;
}

__device__ double cg_coef(int j1, int m1, int j2, int m2, int j3, int m3) {
    if (m1 + m2 != m3) return 0.0;
    int lo = (j1 > j2) ? (j1 - j2) : (j2 - j1);
    if (j3 > j1 + j2 || j3 < lo) return 0.0;
    double pre = (2.0 * j3 + 1.0) * dfact(j3 + j1 - j2) * dfact(j3 - j1 + j2) *
                 dfact(j1 + j2 - j3) / dfact(j1 + j2 + j3 + 1);
    pre *= dfact(j3 + m3) * dfact(j3 - m3) * dfact(j1 - m1) * dfact(j1 + m1) *
           dfact(j2 - m2) * dfact(j2 + m2);
    double s = 0.0;
    for (int k = 0; k <= j1 + j2 - j3; ++k) {
        int a1 = j1 + j2 - j3 - k, a2 = j1 - m1 - k, a3 = j2 + m2 - k;
        int a4 = j3 - j2 + m1 + k, a5 = j3 - j1 - m2 + k;
        if (a1 < 0 || a2 < 0 || a3 < 0 || a4 < 0 || a5 < 0) continue;
        double t = 1.0 / (dfact(k) * dfact(a1) * dfact(a2) * dfact(a3) * dfact(a4) * dfact(a5));
        s += (k & 1) ? -t : t;
    }
    return sqrt(pre) * s;
}

// Q[a][mi] for real-SH basis change (scratch-free, matches reference _q)
__device__ __forceinline__ void qval(int l, int a, int mi, double& re, double& im) {
    re = 0.0; im = 0.0;
    const double inv = 0.7071067811865475244;
    int ma = a - l, mc = mi - l;
    if (ma == 0) { if (mc == 0) re = 1.0; return; }
    if (ma > 0) {
        if (mc == ma)        re = (ma & 1) ? -inv : inv;
        else if (mc == -ma)  re = inv;
    } else {
        int mm = -ma;
        if (mc == ma)        im = inv;
        else if (mc == -ma)  im = -((mm & 1) ? -inv : inv);
    }
}

__global__ void wigner3j_setup() {
    const int L1[11] = {0,0,0,1,1,1,1,2,2,2,2};
    const int L2[11] = {0,1,2,0,1,1,2,0,1,2,2};
    const int L3[11] = {0,1,2,1,0,2,1,2,1,0,2};
    const int p = blockIdx.x;
    const int l1 = L1[p], l2 = L2[p], l3 = L3[p];
    const int d1 = 2 * l1 + 1, d2 = 2 * l2 + 1, d3 = 2 * l3 + 1;
    const int n = d1 * d2 * d3;

    __shared__ double sre[125], sim[125];
    __shared__ double s_scale;
    __shared__ int s_im;

    const int e = threadIdx.x;
    if (e < n) {
        int a = e / (d2 * d3);
        int r = e - a * d2 * d3;
        int b = r / d3;
        int c = r - b * d3;
        double tre = 0.0, tim = 0.0;
        for (int m1 = -l1; m1 <= l1; ++m1) {
            for (int m2 = -l2; m2 <= l2; ++m2) {
                int m3 = -(m1 + m2);
                if (m3 < -l3 || m3 > l3) continue;
                int ex = l1 - l2 - m3;
                double sgn = (ex % 2 != 0) ? -1.0 : 1.0;
                double C = sgn * cg_coef(l1, m1, l2, m2, l3, -m3);
                if (C == 0.0) continue;
                double r1, i1, r2, i2, r3, i3;
                qval(l1, a, m1 + l1, r1, i1);
                qval(l2, b, m2 + l2, r2, i2);
                qval(l3, c, m3 + l3, r3, i3);
                i1 = -i1; i2 = -i2; i3 = -i3;  // conj
                double rr = r1 * r2 - i1 * i2;
                double ri = r1 * i2 + i1 * r2;
                double fr = rr * r3 - ri * i3;
                double fi = rr * i3 + ri * r3;
                tre += C * fr;
                tim += C * fi;
            }
        }
        sre[e] = tre; sim[e] = tim;
    }
    __syncthreads();
    if (threadIdx.x == 0) {
        double sar = 0.0, sai = 0.0;
        for (int i = 0; i < n; ++i) { sar += fabs(sre[i]); sai += fabs(sim[i]); }
        int useim = (sar >= sai) ? 0 : 1;
        double ss = 0.0;
        for (int i = 0; i < n; ++i) { double v = useim ? sim[i] : sre[i]; ss += v * v; }
        s_scale = 1.0 / sqrt(ss);
        s_im = useim;
    }
    __syncthreads();
    if (e < n) {
        double v = s_im ? sim[e] : sre[e];
        g_w3[p * 128 + e] = (float)(v * s_scale);
    }
}

// ---------------- Main tensor-product kernel ---------------------------------
//
// Lane = (z within 16-row tile, w-octet). do_path: held side H in VGPRs
// (chunked), streamed side per s, CG via c[i] precompute, weights as
// per-lane float4x2 VGPR loads (vmcnt-pipelined), acc[8] per lane.
// Wp passed pre-offset by wq*8.  D2 = dim of the x2 irrep (w3 row stride).

template <int DH, int DS, int D2, int DO, bool HX1>
__device__ __forceinline__ void do_path(const float* __restrict__ xh,
                                        const float* __restrict__ xs,
                                        const float* __restrict__ Wp,
                                        const float* __restrict__ w3p,
                                        int k, float* __restrict__ acc) {
    // w3 slice for this k: w3l[held][stream]
    float w3l[DH][DS];
#pragma unroll
    for (int ih = 0; ih < DH; ++ih) {
#pragma unroll
        for (int is = 0; is < DS; ++is) {
            const int i = HX1 ? ih : is;  // x1 component
            const int j = HX1 ? is : ih;  // x2 component
            w3l[ih][is] = w3p[(i * D2 + j) * DO + k];
        }
    }
    constexpr int CH = (DH >= 5) ? 8 : (DH >= 3 ? 16 : 32);  // VGPR cap
#pragma unroll 1
    for (int h0 = 0; h0 < 32; h0 += CH) {
        float H[CH * DH];
#pragma unroll
        for (int h = 0; h < CH; ++h) {
#pragma unroll
            for (int i = 0; i < DH; ++i) H[h * DH + i] = xh[(h0 + h) * DH + i];
        }
#pragma unroll 2
        for (int s = 0; s < 32; ++s) {
            float b[DS];
#pragma unroll
            for (int j = 0; j < DS; ++j) b[j] = xs[s * DS + j];
            float c[DH];
#pragma unroll
            for (int i = 0; i < DH; ++i) {
                float t = 0.f;
#pragma unroll
                for (int j = 0; j < DS; ++j) t = fmaf(w3l[i][j], b[j], t);
                c[i] = t;
            }
#pragma unroll
            for (int h = 0; h < CH; ++h) {
                float o = 0.f;
#pragma unroll
                for (int i = 0; i < DH; ++i) o = fmaf(c[i], H[h * DH + i], o);
                const float* wrow = Wp + (HX1 ? (h0 + h) * 1024 + s * 32
                                              : s * 1024 + (h0 + h) * 32);
                const float4 wa = *reinterpret_cast<const float4*>(wrow);
                const float4 wb = *reinterpret_cast<const float4*>(wrow + 4);
                acc[0] = fmaf(wa.x, o, acc[0]);
                acc[1] = fmaf(wa.y, o, acc[1]);
                acc[2] = fmaf(wa.z, o, acc[2]);
                acc[3] = fmaf(wa.w, o, acc[3]);
                acc[4] = fmaf(wb.x, o, acc[4]);
                acc[5] = fmaf(wb.y, o, acc[5]);
                acc[6] = fmaf(wb.z, o, acc[6]);
                acc[7] = fmaf(wb.w, o, acc[7]);
            }
        }
    }
}

__global__ __launch_bounds__(64, 2) void tp_main(const float* __restrict__ x1,
                                                 const float* __restrict__ x2,
                                                 const float* __restrict__ W,
                                                 float* __restrict__ out) {
    const int lane = threadIdx.x;
    const int zl = lane & 15;
    const int wq = lane >> 4;                  // w-octet 0..3
    const int z = blockIdx.x * 16 + zl;
    const float* r1 = x1 + (size_t)z * 288;
    const float* r2 = x2 + (size_t)z * 288;
    const float* w3t = g_w3;
    const int wo = wq * 8;                     // weight column offset

    float acc[8];
#pragma unroll
    for (int i = 0; i < 8; ++i) acc[i] = 0.f;

    const int arm = blockIdx.y;
    int io, k;
    if (arm == 0)      { io = 0; k = 0; }
    else if (arm <= 3) { io = 1; k = arm - 1; }
    else               { io = 2; k = arm - 4; }

    if (io == 0) {
        // (0,0,0): hold x2(l0), stream x1(l0)
        do_path<1, 1, 1, 1, false>(r2 + 0,   r1 + 0,   W + 0 * 32768 + wo,  w3t + 0 * 128, 0, acc);
        // (1,1,0): hold x2(l1), stream x1(l1)
        do_path<3, 3, 3, 1, false>(r2 + 32,  r1 + 32,  W + 4 * 32768 + wo,  w3t + 4 * 128, 0, acc);
        // (2,2,0): hold x2(l2), stream x1(l2)
        do_path<5, 5, 5, 1, false>(r2 + 128, r1 + 128, W + 9 * 32768 + wo,  w3t + 9 * 128, 0, acc);
    } else if (io == 1) {
        // (0,1,1): hold x1(l0), stream x2(l1)
        do_path<1, 3, 3, 3, true >(r1 + 0,   r2 + 32,  W + 1 * 32768 + wo,  w3t + 1 * 128, k, acc);
        // (1,0,1): hold x2(l0), stream x1(l1)
        do_path<1, 3, 1, 3, false>(r2 + 0,   r1 + 32,  W + 3 * 32768 + wo,  w3t + 3 * 128, k, acc);
        // (1,2,1): hold x1(l1), stream x2(l2)
        do_path<3, 5, 5, 3, true >(r1 + 32,  r2 + 128, W + 6 * 32768 + wo,  w3t + 6 * 128, k, acc);
        // (2,1,1): hold x2(l1), stream x1(l2)
        do_path<3, 5, 3, 3, false>(r2 + 32,  r1 + 128, W + 8 * 32768 + wo,  w3t + 8 * 128, k, acc);
    } else {
        // (0,2,2): hold x1(l0), stream x2(l2)
        do_path<1, 5, 5, 5, true >(r1 + 0,   r2 + 128, W + 2 * 32768 + wo,  w3t + 2 * 128, k, acc);
        // (1,1,2): hold x2(l1), stream x1(l1)
        do_path<3, 3, 3, 5, false>(r2 + 32,  r1 + 32,  W + 5 * 32768 + wo,  w3t + 5 * 128, k, acc);
        // (2,0,2): hold x2(l0), stream x1(l2)  [D2=1: x2 is l0]
        do_path<1, 5, 1, 5, false>(r2 + 0,   r1 + 128, W + 7 * 32768 + wo,  w3t + 7 * 128, k, acc);
        // (2,2,2): hold x2(l2), stream x1(l2)
        do_path<5, 5, 5, 5, false>(r2 + 128, r1 + 128, W + 10 * 32768 + wo, w3t + 10 * 128, k, acc);
    }

    // epilogue: alpha = sqrt((2lo+1)/fan_in)
    const float alpha = (io == 0) ? 0.018042196f : ((io == 1) ? 0.027063294f : 0.034938562f);
    const int off_o   = (io == 0) ? 0 : ((io == 1) ? 32 : 128);
    const int DOd     = (io == 0) ? 1 : ((io == 1) ? 3 : 5);
    float* orow = out + (size_t)z * 288 + off_o + k;
#pragma unroll
    for (int j = 0; j < 8; ++j) orow[(wo + j) * DOd] = alpha * acc[j];
}

// ---------------- launch -----------------------------------------------------

extern "C" void kernel_launch(void* const* d_in, const int* in_sizes, int n_in,
                              void* d_out, int out_size, void* d_ws, size_t ws_size,
                              hipStream_t stream) {
    const float* x1 = (const float*)d_in[0];
    const float* x2 = (const float*)d_in[1];
    const float* W  = (const float*)d_in[2];
    float* out = (float*)d_out;

    wigner3j_setup<<<dim3(11), dim3(128), 0, stream>>>();
    tp_main<<<dim3(512, 9), dim3(64), 0, stream>>>(x1, x2, W, out);
}

// Round 14
// 620.253 us; speedup vs baseline: 2.6114x; 2.0803x over previous
//
#include <hip/hip_runtime.h>

// ============================================================================
// Fully-connected e3nn-style tensor product, IRREPS = 32x0e + 32x1o + 32x2e
// BATCH=8192, FEAT=288, 11 uvw paths, weights flat [360448].
//
// R1 (lane=z, NW=16, grid 128x9x2): 542us, VALU 35%, occ 26% (2.2 waves/SIMD,
//   GRID-limited). FETCH 21MB compulsory, WRITE 9.2MB clean.
// R2 (transpose): 1280us -> REVERTED. R3 (NW=32): 837us -> REVERTED.
//   R1<->R3: waves x2.1 -> time /1.54, per-wave VALU const -> latency-bound.
// R4-R6 (per-lane float4 weight loads): 1290us best -> family REFUTED
//   (L1 request BW swamped; also partial-line WRITE inflation 25MB).
// R7: R1 structure, NW=8, grid (128,9,4) = 4608 blocks = 18 waves/CU (2x R1),
//   s-loop unroll 2 for s_load overlap. Scalar weight loads (s_load) stay.
//   (R13 slot: infra error, never ran — resubmitted unchanged.)
// ============================================================================

__device__ float g_w3[11 * 128];

// ---------------- Wigner 3j setup --------------------------------------------

__device__ __forceinline__ double dfact(int n) {
    double r = 1.0;
    for (int i = 2; i <= n; ++i) r *= (double)i;
    return r;
}

__device__ double cg_coef(int j1, int m1, int j2, int m2, int j3, int m3) {
    if (m1 + m2 != m3) return 0.0;
    int lo = (j1 > j2) ? (j1 - j2) : (j2 - j1);
    if (j3 > j1 + j2 || j3 < lo) return 0.0;
    double pre = (2.0 * j3 + 1.0) * dfact(j3 + j1 - j2) * dfact(j3 - j1 + j2) *
                 dfact(j1 + j2 - j3) / dfact(j1 + j2 + j3 + 1);
    pre *= dfact(j3 + m3) * dfact(j3 - m3) * dfact(j1 - m1) * dfact(j1 + m1) *
           dfact(j2 - m2) * dfact(j2 + m2);
    double s = 0.0;
    for (int k = 0; k <= j1 + j2 - j3; ++k) {
        int a1 = j1 + j2 - j3 - k, a2 = j1 - m1 - k, a3 = j2 + m2 - k;
        int a4 = j3 - j2 + m1 + k, a5 = j3 - j1 - m2 + k;
        if (a1 < 0 || a2 < 0 || a3 < 0 || a4 < 0 || a5 < 0) continue;
        double t = 1.0 / (dfact(k) * dfact(a1) * dfact(a2) * dfact(a3) * dfact(a4) * dfact(a5));
        s += (k & 1) ? -t : t;
    }
    return sqrt(pre) * s;
}

// Q[a][mi] for real-SH basis change (scratch-free, matches reference _q)
__device__ __forceinline__ void qval(int l, int a, int mi, double& re, double& im) {
    re = 0.0; im = 0.0;
    const double inv = 0.7071067811865475244;
    int ma = a - l, mc = mi - l;
    if (ma == 0) { if (mc == 0) re = 1.0; return; }
    if (ma > 0) {
        if (mc == ma)        re = (ma & 1) ? -inv : inv;
        else if (mc == -ma)  re = inv;
    } else {
        int mm = -ma;
        if (mc == ma)        im = inv;
        else if (mc == -ma)  im = -((mm & 1) ? -inv : inv);
    }
}

__global__ void wigner3j_setup() {
    const int L1[11] = {0,0,0,1,1,1,1,2,2,2,2};
    const int L2[11] = {0,1,2,0,1,1,2,0,1,2,2};
    const int L3[11] = {0,1,2,1,0,2,1,2,1,0,2};
    const int p = blockIdx.x;
    const int l1 = L1[p], l2 = L2[p], l3 = L3[p];
    const int d1 = 2 * l1 + 1, d2 = 2 * l2 + 1, d3 = 2 * l3 + 1;
    const int n = d1 * d2 * d3;

    __shared__ double sre[125], sim[125];
    __shared__ double s_scale;
    __shared__ int s_im;

    const int e = threadIdx.x;
    if (e < n) {
        int a = e / (d2 * d3);
        int r = e - a * d2 * d3;
        int b = r / d3;
        int c = r - b * d3;
        double tre = 0.0, tim = 0.0;
        for (int m1 = -l1; m1 <= l1; ++m1) {
            for (int m2 = -l2; m2 <= l2; ++m2) {
                int m3 = -(m1 + m2);
                if (m3 < -l3 || m3 > l3) continue;
                int ex = l1 - l2 - m3;
                double sgn = (ex % 2 != 0) ? -1.0 : 1.0;
                double C = sgn * cg_coef(l1, m1, l2, m2, l3, -m3);
                if (C == 0.0) continue;
                double r1, i1, r2, i2, r3, i3;
                qval(l1, a, m1 + l1, r1, i1);
                qval(l2, b, m2 + l2, r2, i2);
                qval(l3, c, m3 + l3, r3, i3);
                i1 = -i1; i2 = -i2; i3 = -i3;  // conj
                double rr = r1 * r2 - i1 * i2;
                double ri = r1 * i2 + i1 * r2;
                double fr = rr * r3 - ri * i3;
                double fi = rr * i3 + ri * r3;
                tre += C * fr;
                tim += C * fi;
            }
        }
        sre[e] = tre; sim[e] = tim;
    }
    __syncthreads();
    if (threadIdx.x == 0) {
        double sar = 0.0, sai = 0.0;
        for (int i = 0; i < n; ++i) { sar += fabs(sre[i]); sai += fabs(sim[i]); }
        int useim = (sar >= sai) ? 0 : 1;
        double ss = 0.0;
        for (int i = 0; i < n; ++i) { double v = useim ? sim[i] : sre[i]; ss += v * v; }
        s_scale = 1.0 / sqrt(ss);
        s_im = useim;
    }
    __syncthreads();
    if (e < n) {
        double v = s_im ? sim[e] : sre[e];
        g_w3[p * 128 + e] = (float)(v * s_scale);
    }
}

// ---------------- Main tensor-product kernel ---------------------------------
//
// Lane = z (batch row). do_path: held side (DH comps/channel, 32 channels in
// VGPRs, chunked), streamed side per channel, CG via c[i] precompute, weights
// wave-uniform (s_load rows of NW=8), acc[8] per lane. One writer per output.

template <int DH, int DS, int D1, int D2, int DO, bool HX1, int NW>
__device__ __forceinline__ void do_path(const float* __restrict__ xh,
                                        const float* __restrict__ xs,
                                        const float* __restrict__ Wp,
                                        const float* __restrict__ w3p,
                                        int k, float* __restrict__ acc) {
    // w3 slice for this k: w3l[held][stream]
    float w3l[DH][DS];
#pragma unroll
    for (int ih = 0; ih < DH; ++ih) {
#pragma unroll
        for (int is = 0; is < DS; ++is) {
            const int i = HX1 ? ih : is;  // x1 component
            const int j = HX1 ? is : ih;  // x2 component
            w3l[ih][is] = w3p[(i * D2 + j) * DO + k];
        }
    }
    constexpr int CH = (DH >= 5) ? 16 : 32;  // held-channel chunk (VGPR cap)
#pragma unroll 1
    for (int h0 = 0; h0 < 32; h0 += CH) {
        float H[CH * DH];
#pragma unroll
        for (int h = 0; h < CH; ++h) {
#pragma unroll
            for (int i = 0; i < DH; ++i) H[h * DH + i] = xh[(h0 + h) * DH + i];
        }
#pragma unroll 2
        for (int s = 0; s < 32; ++s) {
            float b[DS];
#pragma unroll
            for (int j = 0; j < DS; ++j) b[j] = xs[s * DS + j];
            float c[DH];
#pragma unroll
            for (int i = 0; i < DH; ++i) {
                float t = 0.f;
#pragma unroll
                for (int j = 0; j < DS; ++j) t = fmaf(w3l[i][j], b[j], t);
                c[i] = t;
            }
            const float* wbase = Wp + (HX1 ? s * 32 : s * 1024);
#pragma unroll
            for (int h = 0; h < CH; ++h) {
                float o = 0.f;
#pragma unroll
                for (int i = 0; i < DH; ++i) o = fmaf(c[i], H[h * DH + i], o);
                const float* wr = wbase + (HX1 ? (h0 + h) * 1024 : (h0 + h) * 32);
#pragma unroll
                for (int w = 0; w < NW; ++w) acc[w] = fmaf(wr[w], o, acc[w]);
            }
        }
    }
}

__global__ __launch_bounds__(64, 2) void tp_main(const float* __restrict__ x1,
                                                 const float* __restrict__ x2,
                                                 const float* __restrict__ W,
                                                 float* __restrict__ out) {
    const int z = blockIdx.x * 64 + threadIdx.x;
    const float* r1 = x1 + (size_t)z * 288;
    const float* r2 = x2 + (size_t)z * 288;
    const int w0 = blockIdx.z * 8;             // w-octet of this block
    const float* w3t = g_w3;

    float acc[8];
#pragma unroll
    for (int i = 0; i < 8; ++i) acc[i] = 0.f;

    const int arm = blockIdx.y;
    int io, k;
    if (arm == 0)      { io = 0; k = 0; }
    else if (arm <= 3) { io = 1; k = arm - 1; }
    else               { io = 2; k = arm - 4; }

    if (io == 0) {
        // (0,0,0): hold x2(l0), stream x1(l0)
        do_path<1, 1, 1, 1, 1, false, 8>(r2 + 0,   r1 + 0,   W + 0 * 32768 + w0,  w3t + 0 * 128, 0, acc);
        // (1,1,0): hold x2(l1), stream x1(l1)
        do_path<3, 3, 3, 3, 1, false, 8>(r2 + 32,  r1 + 32,  W + 4 * 32768 + w0,  w3t + 4 * 128, 0, acc);
        // (2,2,0): hold x2(l2), stream x1(l2)
        do_path<5, 5, 5, 5, 1, false, 8>(r2 + 128, r1 + 128, W + 9 * 32768 + w0,  w3t + 9 * 128, 0, acc);
    } else if (io == 1) {
        // (0,1,1): hold x1(l0), stream x2(l1)
        do_path<1, 3, 1, 3, 3, true,  8>(r1 + 0,   r2 + 32,  W + 1 * 32768 + w0,  w3t + 1 * 128, k, acc);
        // (1,0,1): hold x2(l0), stream x1(l1)
        do_path<1, 3, 3, 1, 3, false, 8>(r2 + 0,   r1 + 32,  W + 3 * 32768 + w0,  w3t + 3 * 128, k, acc);
        // (1,2,1): hold x1(l1), stream x2(l2)
        do_path<3, 5, 3, 5, 3, true,  8>(r1 + 32,  r2 + 128, W + 6 * 32768 + w0,  w3t + 6 * 128, k, acc);
        // (2,1,1): hold x2(l1), stream x1(l2)
        do_path<3, 5, 5, 3, 3, false, 8>(r2 + 32,  r1 + 128, W + 8 * 32768 + w0,  w3t + 8 * 128, k, acc);
    } else {
        // (0,2,2): hold x1(l0), stream x2(l2)
        do_path<1, 5, 1, 5, 5, true,  8>(r1 + 0,   r2 + 128, W + 2 * 32768 + w0,  w3t + 2 * 128, k, acc);
        // (1,1,2): hold x2(l1), stream x1(l1)
        do_path<3, 3, 3, 3, 5, false, 8>(r2 + 32,  r1 + 32,  W + 5 * 32768 + w0,  w3t + 5 * 128, k, acc);
        // (2,0,2): hold x2(l0), stream x1(l2)
        do_path<1, 5, 5, 1, 5, false, 8>(r2 + 0,   r1 + 128, W + 7 * 32768 + w0,  w3t + 7 * 128, k, acc);
        // (2,2,2): hold x2(l2), stream x1(l2)
        do_path<5, 5, 5, 5, 5, false, 8>(r2 + 128, r1 + 128, W + 10 * 32768 + w0, w3t + 10 * 128, k, acc);
    }

    // epilogue: alpha = sqrt((2lo+1)/fan_in)
    const float alpha = (io == 0) ? 0.018042196f : ((io == 1) ? 0.027063294f : 0.034938562f);
    const int off_o   = (io == 0) ? 0 : ((io == 1) ? 32 : 128);
    const int DOd     = (io == 0) ? 1 : ((io == 1) ? 3 : 5);
    float* orow = out + (size_t)z * 288 + off_o + k;
#pragma unroll
    for (int w = 0; w < 8; ++w) orow[(w0 + w) * DOd] = alpha * acc[w];
}

// ---------------- launch -----------------------------------------------------

extern "C" void kernel_launch(void* const* d_in, const int* in_sizes, int n_in,
                              void* d_out, int out_size, void* d_ws, size_t ws_size,
                              hipStream_t stream) {
    const float* x1 = (const float*)d_in[0];
    const float* x2 = (const float*)d_in[1];
    const float* W  = (const float*)d_in[2];
    float* out = (float*)d_out;

    wigner3j_setup<<<dim3(11), dim3(128), 0, stream>>>();
    tp_main<<<dim3(128, 9, 4), dim3(64), 0, stream>>>(x1, x2, W, out);
}

// Round 15
// 498.278 us; speedup vs baseline: 3.2507x; 1.2448x over previous
//
#include <hip/hip_runtime.h>

// ============================================================================
// Fully-connected e3nn-style tensor product, IRREPS = 32x0e + 32x1o + 32x2e
// BATCH=8192, FEAT=288, 11 uvw paths, weights flat [360448].
//
// R1 (lane=z, NW=16, grid 128x9x2): 542us, VALU 35%, occ 26%. BEST.
// R2 transpose 1280 / R3 NW=32 837 / R4-R6 per-lane weights 1290: REVERTED.
// R7 (NW=8, grid x2): 620us, occ STILL ~28% -> resident waves cap at ~9/CU
//   regardless of grid; VALU-seconds conserved. Wave-count lever dead.
// R8: R1 envelope exactly (NW=16, grid 128x9x2, s_load weights), but all
//   x-side loads vectorized to provably-16B-aligned float4s via s-groups of
//   4 (DS f4/group vs 4*DS scalars) and f4 H-chunk loads. 4x fewer gather
//   instructions -> tests the TA/L1-request-throughput theory.
// ============================================================================

__device__ float g_w3[11 * 128];

// ---------------- Wigner 3j setup --------------------------------------------

__device__ __forceinline__ double dfact(int n) {
    double r = 1.0;
    for (int i = 2; i <= n; ++i) r *= (double)i;
    return r;
}

__device__ double cg_coef(int j1, int m1, int j2, int m2, int j3, int m3) {
    if (m1 + m2 != m3) return 0.0;
    int lo = (j1 > j2) ? (j1 - j2) : (j2 - j1);
    if (j3 > j1 + j2 || j3 < lo) return 0.0;
    double pre = (2.0 * j3 + 1.0) * dfact(j3 + j1 - j2) * dfact(j3 - j1 + j2) *
                 dfact(j1 + j2 - j3) / dfact(j1 + j2 + j3 + 1);
    pre *= dfact(j3 + m3) * dfact(j3 - m3) * dfact(j1 - m1) * dfact(j1 + m1) *
           dfact(j2 - m2) * dfact(j2 + m2);
    double s = 0.0;
    for (int k = 0; k <= j1 + j2 - j3; ++k) {
        int a1 = j1 + j2 - j3 - k, a2 = j1 - m1 - k, a3 = j2 + m2 - k;
        int a4 = j3 - j2 + m1 + k, a5 = j3 - j1 - m2 + k;
        if (a1 < 0 || a2 < 0 || a3 < 0 || a4 < 0 || a5 < 0) continue;
        double t = 1.0 / (dfact(k) * dfact(a1) * dfact(a2) * dfact(a3) * dfact(a4) * dfact(a5));
        s += (k & 1) ? -t : t;
    }
    return sqrt(pre) * s;
}

// Q[a][mi] for real-SH basis change (scratch-free, matches reference _q)
__device__ __forceinline__ void qval(int l, int a, int mi, double& re, double& im) {
    re = 0.0; im = 0.0;
    const double inv = 0.7071067811865475244;
    int ma = a - l, mc = mi - l;
    if (ma == 0) { if (mc == 0) re = 1.0; return; }
    if (ma > 0) {
        if (mc == ma)        re = (ma & 1) ? -inv : inv;
        else if (mc == -ma)  re = inv;
    } else {
        int mm = -ma;
        if (mc == ma)        im = inv;
        else if (mc == -ma)  im = -((mm & 1) ? -inv : inv);
    }
}

__global__ void wigner3j_setup() {
    const int L1[11] = {0,0,0,1,1,1,1,2,2,2,2};
    const int L2[11] = {0,1,2,0,1,1,2,0,1,2,2};
    const int L3[11] = {0,1,2,1,0,2,1,2,1,0,2};
    const int p = blockIdx.x;
    const int l1 = L1[p], l2 = L2[p], l3 = L3[p];
    const int d1 = 2 * l1 + 1, d2 = 2 * l2 + 1, d3 = 2 * l3 + 1;
    const int n = d1 * d2 * d3;

    __shared__ double sre[125], sim[125];
    __shared__ double s_scale;
    __shared__ int s_im;

    const int e = threadIdx.x;
    if (e < n) {
        int a = e / (d2 * d3);
        int r = e - a * d2 * d3;
        int b = r / d3;
        int c = r - b * d3;
        double tre = 0.0, tim = 0.0;
        for (int m1 = -l1; m1 <= l1; ++m1) {
            for (int m2 = -l2; m2 <= l2; ++m2) {
                int m3 = -(m1 + m2);
                if (m3 < -l3 || m3 > l3) continue;
                int ex = l1 - l2 - m3;
                double sgn = (ex % 2 != 0) ? -1.0 : 1.0;
                double C = sgn * cg_coef(l1, m1, l2, m2, l3, -m3);
                if (C == 0.0) continue;
                double r1, i1, r2, i2, r3, i3;
                qval(l1, a, m1 + l1, r1, i1);
                qval(l2, b, m2 + l2, r2, i2);
                qval(l3, c, m3 + l3, r3, i3);
                i1 = -i1; i2 = -i2; i3 = -i3;  // conj
                double rr = r1 * r2 - i1 * i2;
                double ri = r1 * i2 + i1 * r2;
                double fr = rr * r3 - ri * i3;
                double fi = rr * i3 + ri * r3;
                tre += C * fr;
                tim += C * fi;
            }
        }
        sre[e] = tre; sim[e] = tim;
    }
    __syncthreads();
    if (threadIdx.x == 0) {
        double sar = 0.0, sai = 0.0;
        for (int i = 0; i < n; ++i) { sar += fabs(sre[i]); sai += fabs(sim[i]); }
        int useim = (sar >= sai) ? 0 : 1;
        double ss = 0.0;
        for (int i = 0; i < n; ++i) { double v = useim ? sim[i] : sre[i]; ss += v * v; }
        s_scale = 1.0 / sqrt(ss);
        s_im = useim;
    }
    __syncthreads();
    if (e < n) {
        double v = s_im ? sim[e] : sre[e];
        g_w3[p * 128 + e] = (float)(v * s_scale);
    }
}

// ---------------- Main tensor-product kernel ---------------------------------
//
// Lane = z (batch row). Held side H in VGPRs (float4 chunk loads), streamed
// side loaded per s-GROUP of 4 as DS aligned float4s, CG via c[i] precompute,
// weights wave-uniform (s_load), NW=16 outs into acc. One writer per output.
// All float4 loads are provably 16B-aligned: row stride 1152B, irrep offsets
// {0,128,512}B, group stride 4*DS*4B in {16,48,80}, chunk offset 320B.

__device__ __forceinline__ float f4c(const float4& v, int c) {
    switch (c & 3) {
        case 0:  return v.x;
        case 1:  return v.y;
        case 2:  return v.z;
        default: return v.w;
    }
}

template <int DH, int DS, int D1, int D2, int DO, bool HX1, int NW>
__device__ __forceinline__ void do_path(const float* __restrict__ xh,
                                        const float* __restrict__ xs,
                                        const float* __restrict__ Wp,
                                        const float* __restrict__ w3p,
                                        int k, float* __restrict__ acc) {
    // w3 slice for this k: w3l[held][stream]
    float w3l[DH][DS];
#pragma unroll
    for (int ih = 0; ih < DH; ++ih) {
#pragma unroll
        for (int is = 0; is < DS; ++is) {
            const int i = HX1 ? ih : is;  // x1 component
            const int j = HX1 ? is : ih;  // x2 component
            w3l[ih][is] = w3p[(i * D2 + j) * DO + k];
        }
    }
    constexpr int CH = (DH >= 5) ? 16 : 32;  // held-channel chunk (VGPR cap)
    static_assert((CH * DH) % 4 == 0, "H chunk must be float4-tileable");
#pragma unroll 1
    for (int h0 = 0; h0 < 32; h0 += CH) {
        float H[CH * DH];
#pragma unroll
        for (int q = 0; q < CH * DH / 4; ++q) {
            const float4 v = *reinterpret_cast<const float4*>(xh + h0 * DH + q * 4);
            H[q * 4 + 0] = v.x; H[q * 4 + 1] = v.y;
            H[q * 4 + 2] = v.z; H[q * 4 + 3] = v.w;
        }
#pragma unroll 2
        for (int g = 0; g < 8; ++g) {        // s in groups of 4
            float4 bg[DS];                   // 4*DS floats = DS float4s
#pragma unroll
            for (int q = 0; q < DS; ++q)
                bg[q] = *reinterpret_cast<const float4*>(xs + g * 4 * DS + q * 4);
#pragma unroll
            for (int t = 0; t < 4; ++t) {
                const int s = g * 4 + t;
                float c[DH];
#pragma unroll
                for (int i = 0; i < DH; ++i) {
                    float cv = 0.f;
#pragma unroll
                    for (int j = 0; j < DS; ++j) {
                        const int e = t * DS + j;      // compile-time in unroll
                        cv = fmaf(w3l[i][j], f4c(bg[e >> 2], e), cv);
                    }
                    c[i] = cv;
                }
                const float* wbase = Wp + (HX1 ? s * 32 : s * 1024);
#pragma unroll
                for (int h = 0; h < CH; ++h) {
                    float o = 0.f;
#pragma unroll
                    for (int i = 0; i < DH; ++i) o = fmaf(c[i], H[h * DH + i], o);
                    const float* wr = wbase + (HX1 ? (h0 + h) * 1024 : (h0 + h) * 32);
#pragma unroll
                    for (int w = 0; w < NW; ++w) acc[w] = fmaf(wr[w], o, acc[w]);
                }
            }
        }
    }
}

__global__ __launch_bounds__(64, 2) void tp_main(const float* __restrict__ x1,
                                                 const float* __restrict__ x2,
                                                 const float* __restrict__ W,
                                                 float* __restrict__ out) {
    const int z = blockIdx.x * 64 + threadIdx.x;
    const float* r1 = x1 + (size_t)z * 288;
    const float* r2 = x2 + (size_t)z * 288;
    const int w0 = blockIdx.z * 16;
    const float* w3t = g_w3;

    float acc[16];
#pragma unroll
    for (int i = 0; i < 16; ++i) acc[i] = 0.f;

    const int arm = blockIdx.y;
    int io, k;
    if (arm == 0)      { io = 0; k = 0; }
    else if (arm <= 3) { io = 1; k = arm - 1; }
    else               { io = 2; k = arm - 4; }

    if (io == 0) {
        // (0,0,0): hold x2(l0), stream x1(l0)
        do_path<1, 1, 1, 1, 1, false, 16>(r2 + 0,   r1 + 0,   W + 0 * 32768 + w0,  w3t + 0 * 128, 0, acc);
        // (1,1,0): hold x2(l1), stream x1(l1)
        do_path<3, 3, 3, 3, 1, false, 16>(r2 + 32,  r1 + 32,  W + 4 * 32768 + w0,  w3t + 4 * 128, 0, acc);
        // (2,2,0): hold x2(l2), stream x1(l2)
        do_path<5, 5, 5, 5, 1, false, 16>(r2 + 128, r1 + 128, W + 9 * 32768 + w0,  w3t + 9 * 128, 0, acc);
    } else if (io == 1) {
        // (0,1,1): hold x1(l0), stream x2(l1)
        do_path<1, 3, 1, 3, 3, true,  16>(r1 + 0,   r2 + 32,  W + 1 * 32768 + w0,  w3t + 1 * 128, k, acc);
        // (1,0,1): hold x2(l0), stream x1(l1)
        do_path<1, 3, 3, 1, 3, false, 16>(r2 + 0,   r1 + 32,  W + 3 * 32768 + w0,  w3t + 3 * 128, k, acc);
        // (1,2,1): hold x1(l1), stream x2(l2)
        do_path<3, 5, 3, 5, 3, true,  16>(r1 + 32,  r2 + 128, W + 6 * 32768 + w0,  w3t + 6 * 128, k, acc);
        // (2,1,1): hold x2(l1), stream x1(l2)
        do_path<3, 5, 5, 3, 3, false, 16>(r2 + 32,  r1 + 128, W + 8 * 32768 + w0,  w3t + 8 * 128, k, acc);
    } else {
        // (0,2,2): hold x1(l0), stream x2(l2)
        do_path<1, 5, 1, 5, 5, true,  16>(r1 + 0,   r2 + 128, W + 2 * 32768 + w0,  w3t + 2 * 128, k, acc);
        // (1,1,2): hold x2(l1), stream x1(l1)
        do_path<3, 3, 3, 3, 5, false, 16>(r2 + 32,  r1 + 32,  W + 5 * 32768 + w0,  w3t + 5 * 128, k, acc);
        // (2,0,2): hold x2(l0), stream x1(l2)
        do_path<1, 5, 5, 1, 5, false, 16>(r2 + 0,   r1 + 128, W + 7 * 32768 + w0,  w3t + 7 * 128, k, acc);
        // (2,2,2): hold x2(l2), stream x1(l2)
        do_path<5, 5, 5, 5, 5, false, 16>(r2 + 128, r1 + 128, W + 10 * 32768 + w0, w3t + 10 * 128, k, acc);
    }

    // epilogue: alpha = sqrt((2lo+1)/fan_in)
    const float alpha = (io == 0) ? 0.018042196f : ((io == 1) ? 0.027063294f : 0.034938562f);
    const int off_o   = (io == 0) ? 0 : ((io == 1) ? 32 : 128);
    const int DOd     = (io == 0) ? 1 : ((io == 1) ? 3 : 5);
    float* orow = out + (size_t)z * 288 + off_o + k;
#pragma unroll
    for (int w = 0; w < 16; ++w) orow[(w0 + w) * DOd] = alpha * acc[w];
}

// ---------------- launch -----------------------------------------------------

extern "C" void kernel_launch(void* const* d_in, const int* in_sizes, int n_in,
                              void* d_out, int out_size, void* d_ws, size_t ws_size,
                              hipStream_t stream) {
    const float* x1 = (const float*)d_in[0];
    const float* x2 = (const float*)d_in[1];
    const float* W  = (const float*)d_in[2];
    float* out = (float*)d_out;

    wigner3j_setup<<<dim3(11), dim3(128), 0, stream>>>();
    tp_main<<<dim3(128, 9, 2), dim3(64), 0, stream>>>(x1, x2, W, out);
}

// Round 16
// 474.525 us; speedup vs baseline: 3.4134x; 1.0501x over previous
//
#include <hip/hip_runtime.h>

// ============================================================================
// Fully-connected e3nn-style tensor product, IRREPS = 32x0e + 32x1o + 32x2e
// BATCH=8192, FEAT=288, 11 uvw paths, weights flat [360448].
//
// R1 (lane=z, NW=16): 542us, VALU 35%. R8 (+f4 x-loads): 498us, VALU 33%.
// R2/R3/R4-R7: transpose, NW=32, per-lane weights, grid x2 -> all REVERTED.
//   Wave-count lever dead (resident waves cap ~9/CU); x-gathers minor.
//   VALU floor ~155us; 3x stall = SGPR-serialized s_load weight rows
//   (dwordx16 = 16 SGPRs/row, only 2-3 in flight under 112 SGPRs).
// R9: stage weight tiles (8KB = ST s x CH h x 16 w) into LDS via 8x
//   global_load_lds dwordx4 (vector pipe, no dependents until tile edge),
//   double-buffered, counted s_waitcnt vmcnt(8) prefetch. Hot loop reads
//   rows as broadcast ds_read_b128 (conflict-free, lgkm-pipelined).
// ============================================================================

__device__ float g_w3[11 * 128];

// ---------------- Wigner 3j setup --------------------------------------------

__device__ __forceinline__ double dfact(int n) {
    double r = 1.0;
    for (int i = 2; i <= n; ++i) r *= (double)i;
    return r;
}

__device__ double cg_coef(int j1, int m1, int j2, int m2, int j3, int m3) {
    if (m1 + m2 != m3) return 0.0;
    int lo = (j1 > j2) ? (j1 - j2) : (j2 - j1);
    if (j3 > j1 + j2 || j3 < lo) return 0.0;
    double pre = (2.0 * j3 + 1.0) * dfact(j3 + j1 - j2) * dfact(j3 - j1 + j2) *
                 dfact(j1 + j2 - j3) / dfact(j1 + j2 + j3 + 1);
    pre *= dfact(j3 + m3) * dfact(j3 - m3) * dfact(j1 - m1) * dfact(j1 + m1) *
           dfact(j2 - m2) * dfact(j2 + m2);
    double s = 0.0;
    for (int k = 0; k <= j1 + j2 - j3; ++k) {
        int a1 = j1 + j2 - j3 - k, a2 = j1 - m1 - k, a3 = j2 + m2 - k;
        int a4 = j3 - j2 + m1 + k, a5 = j3 - j1 - m2 + k;
        if (a1 < 0 || a2 < 0 || a3 < 0 || a4 < 0 || a5 < 0) continue;
        double t = 1.0 / (dfact(k) * dfact(a1) * dfact(a2) * dfact(a3) * dfact(a4) * dfact(a5));
        s += (k & 1) ? -t : t;
    }
    return sqrt(pre) * s;
}

// Q[a][mi] for real-SH basis change (scratch-free, matches reference _q)
__device__ __forceinline__ void qval(int l, int a, int mi, double& re, double& im) {
    re = 0.0; im = 0.0;
    const double inv = 0.7071067811865475244;
    int ma = a - l, mc = mi - l;
    if (ma == 0) { if (mc == 0) re = 1.0; return; }
    if (ma > 0) {
        if (mc == ma)        re = (ma & 1) ? -inv : inv;
        else if (mc == -ma)  re = inv;
    } else {
        int mm = -ma;
        if (mc == ma)        im = inv;
        else if (mc == -ma)  im = -((mm & 1) ? -inv : inv);
    }
}

__global__ void wigner3j_setup() {
    const int L1[11] = {0,0,0,1,1,1,1,2,2,2,2};
    const int L2[11] = {0,1,2,0,1,1,2,0,1,2,2};
    const int L3[11] = {0,1,2,1,0,2,1,2,1,0,2};
    const int p = blockIdx.x;
    const int l1 = L1[p], l2 = L2[p], l3 = L3[p];
    const int d1 = 2 * l1 + 1, d2 = 2 * l2 + 1, d3 = 2 * l3 + 1;
    const int n = d1 * d2 * d3;

    __shared__ double sre[125], sim[125];
    __shared__ double s_scale;
    __shared__ int s_im;

    const int e = threadIdx.x;
    if (e < n) {
        int a = e / (d2 * d3);
        int r = e - a * d2 * d3;
        int b = r / d3;
        int c = r - b * d3;
        double tre = 0.0, tim = 0.0;
        for (int m1 = -l1; m1 <= l1; ++m1) {
            for (int m2 = -l2; m2 <= l2; ++m2) {
                int m3 = -(m1 + m2);
                if (m3 < -l3 || m3 > l3) continue;
                int ex = l1 - l2 - m3;
                double sgn = (ex % 2 != 0) ? -1.0 : 1.0;
                double C = sgn * cg_coef(l1, m1, l2, m2, l3, -m3);
                if (C == 0.0) continue;
                double r1, i1, r2, i2, r3, i3;
                qval(l1, a, m1 + l1, r1, i1);
                qval(l2, b, m2 + l2, r2, i2);
                qval(l3, c, m3 + l3, r3, i3);
                i1 = -i1; i2 = -i2; i3 = -i3;  // conj
                double rr = r1 * r2 - i1 * i2;
                double ri = r1 * i2 + i1 * r2;
                double fr = rr * r3 - ri * i3;
                double fi = rr * i3 + ri * r3;
                tre += C * fr;
                tim += C * fi;
            }
        }
        sre[e] = tre; sim[e] = tim;
    }
    __syncthreads();
    if (threadIdx.x == 0) {
        double sar = 0.0, sai = 0.0;
        for (int i = 0; i < n; ++i) { sar += fabs(sre[i]); sai += fabs(sim[i]); }
        int useim = (sar >= sai) ? 0 : 1;
        double ss = 0.0;
        for (int i = 0; i < n; ++i) { double v = useim ? sim[i] : sre[i]; ss += v * v; }
        s_scale = 1.0 / sqrt(ss);
        s_im = useim;
    }
    __syncthreads();
    if (e < n) {
        double v = s_im ? sim[e] : sre[e];
        g_w3[p * 128 + e] = (float)(v * s_scale);
    }
}

// ---------------- Main tensor-product kernel ---------------------------------
//
// Lane = z (batch row). Weight tiles staged to LDS (vector pipe), hot loop
// reads rows as broadcast ds_read_b128. x-side: f4 loads (all provably
// 16B-aligned). CG via c[i] precompute. NW=16 outs. One writer per output.

__device__ __forceinline__ float f4c(const float4& v, int c) {
    switch (c & 3) {
        case 0:  return v.x;
        case 1:  return v.y;
        case 2:  return v.z;
        default: return v.w;
    }
}

// Stage one weight tile: rows (s0..s0+ST-1) x (h0..h0+CH-1), 16 w columns,
// ST*CH = 128 rows of 64B = 8KB = 8 x global_load_lds(dwordx4).
// LDS layout: row (ss*CH + h) at byte offset row*64.
template <bool HX1, int CH>
__device__ __forceinline__ void stage(const float* __restrict__ Wp,
                                      float* buf, int s0, int h0, int lane) {
#pragma unroll
    for (int q = 0; q < 8; ++q) {
        const int r = q * 16 + (lane >> 2);
        const int seg = lane & 3;
        const int s = s0 + ((CH == 16) ? (r >> 4) : (r >> 5));
        const int h = h0 + ((CH == 16) ? (r & 15) : (r & 31));
        const float* g = Wp + (HX1 ? h * 1024 + s * 32 : s * 1024 + h * 32) + seg * 4;
        __builtin_amdgcn_global_load_lds(
            (const __attribute__((address_space(1))) unsigned int*)g,
            (__attribute__((address_space(3))) unsigned int*)(buf + q * 256),
            16, 0, 0);
    }
}

template <int DH, int DS, int D2, int DO, bool HX1>
__device__ __forceinline__ void do_path(const float* __restrict__ xh,
                                        const float* __restrict__ xs,
                                        const float* __restrict__ Wp,
                                        const float* __restrict__ w3p,
                                        int k, float* __restrict__ acc,
                                        float (&lds)[2][2048], int lane) {
    // w3 slice for this k: w3l[held][stream]
    float w3l[DH][DS];
#pragma unroll
    for (int ih = 0; ih < DH; ++ih) {
#pragma unroll
        for (int is = 0; is < DS; ++is) {
            const int i = HX1 ? ih : is;  // x1 component
            const int j = HX1 ? is : ih;  // x2 component
            w3l[ih][is] = w3p[(i * D2 + j) * DO + k];
        }
    }
    constexpr int CH = (DH >= 5) ? 16 : 32;  // held-channel chunk
    constexpr int ST = (DH >= 5) ? 8 : 4;    // s per tile (tile = 8KB)
    constexpr int NT = 32 / ST;              // tiles per h-chunk
    static_assert((CH * DH) % 4 == 0, "H chunk must be float4-tileable");
#pragma unroll 1
    for (int h0 = 0; h0 < 32; h0 += CH) {
        float H[CH * DH];
#pragma unroll
        for (int q = 0; q < CH * DH / 4; ++q) {
            const float4 v = *reinterpret_cast<const float4*>(xh + h0 * DH + q * 4);
            H[q * 4 + 0] = v.x; H[q * 4 + 1] = v.y;
            H[q * 4 + 2] = v.z; H[q * 4 + 3] = v.w;
        }
        stage<HX1, CH>(Wp, &lds[0][0], 0, h0, lane);
#pragma unroll 1
        for (int t = 0; t < NT; ++t) {
            if (t + 1 < NT) {
                stage<HX1, CH>(Wp, &lds[(t + 1) & 1][0], (t + 1) * ST, h0, lane);
                asm volatile("s_waitcnt vmcnt(8)" ::: "memory");
            } else {
                asm volatile("s_waitcnt vmcnt(0)" ::: "memory");
            }
            const float* wbuf = &lds[t & 1][0];
#pragma unroll
            for (int g = 0; g < ST / 4; ++g) {
                float4 bg[DS];  // 4 s-values worth of streamed side
#pragma unroll
                for (int q = 0; q < DS; ++q)
                    bg[q] = *reinterpret_cast<const float4*>(
                        xs + (t * ST + g * 4) * DS + q * 4);
#pragma unroll
                for (int tt = 0; tt < 4; ++tt) {
                    const int ss = g * 4 + tt;  // s within tile
                    float c[DH];
#pragma unroll
                    for (int i = 0; i < DH; ++i) {
                        float cv = 0.f;
#pragma unroll
                        for (int j = 0; j < DS; ++j) {
                            const int e = tt * DS + j;  // compile-time in unroll
                            cv = fmaf(w3l[i][j], f4c(bg[e >> 2], e), cv);
                        }
                        c[i] = cv;
                    }
#pragma unroll
                    for (int h = 0; h < CH; ++h) {
                        float o = 0.f;
#pragma unroll
                        for (int i = 0; i < DH; ++i) o = fmaf(c[i], H[h * DH + i], o);
                        const float* wr = wbuf + (ss * CH + h) * 16;
                        const float4 wa = *reinterpret_cast<const float4*>(wr);
                        const float4 wb = *reinterpret_cast<const float4*>(wr + 4);
                        const float4 wc = *reinterpret_cast<const float4*>(wr + 8);
                        const float4 wd = *reinterpret_cast<const float4*>(wr + 12);
                        acc[0]  = fmaf(wa.x, o, acc[0]);
                        acc[1]  = fmaf(wa.y, o, acc[1]);
                        acc[2]  = fmaf(wa.z, o, acc[2]);
                        acc[3]  = fmaf(wa.w, o, acc[3]);
                        acc[4]  = fmaf(wb.x, o, acc[4]);
                        acc[5]  = fmaf(wb.y, o, acc[5]);
                        acc[6]  = fmaf(wb.z, o, acc[6]);
                        acc[7]  = fmaf(wb.w, o, acc[7]);
                        acc[8]  = fmaf(wc.x, o, acc[8]);
                        acc[9]  = fmaf(wc.y, o, acc[9]);
                        acc[10] = fmaf(wc.z, o, acc[10]);
                        acc[11] = fmaf(wc.w, o, acc[11]);
                        acc[12] = fmaf(wd.x, o, acc[12]);
                        acc[13] = fmaf(wd.y, o, acc[13]);
                        acc[14] = fmaf(wd.z, o, acc[14]);
                        acc[15] = fmaf(wd.w, o, acc[15]);
                    }
                }
            }
        }
    }
}

__global__ __launch_bounds__(64, 2) void tp_main(const float* __restrict__ x1,
                                                 const float* __restrict__ x2,
                                                 const float* __restrict__ W,
                                                 float* __restrict__ out) {
    __shared__ float lds[2][2048];  // 2 x 8KB weight tiles
    const int lane = threadIdx.x;
    const int z = blockIdx.x * 64 + lane;
    const float* r1 = x1 + (size_t)z * 288;
    const float* r2 = x2 + (size_t)z * 288;
    const int w0 = blockIdx.z * 16;
    const float* w3t = g_w3;

    float acc[16];
#pragma unroll
    for (int i = 0; i < 16; ++i) acc[i] = 0.f;

    const int arm = blockIdx.y;
    int io, k;
    if (arm == 0)      { io = 0; k = 0; }
    else if (arm <= 3) { io = 1; k = arm - 1; }
    else               { io = 2; k = arm - 4; }

    if (io == 0) {
        // (0,0,0): hold x2(l0), stream x1(l0)
        do_path<1, 1, 1, 1, false>(r2 + 0,   r1 + 0,   W + 0 * 32768 + w0,  w3t + 0 * 128, 0, acc, lds, lane);
        // (1,1,0): hold x2(l1), stream x1(l1)
        do_path<3, 3, 3, 1, false>(r2 + 32,  r1 + 32,  W + 4 * 32768 + w0,  w3t + 4 * 128, 0, acc, lds, lane);
        // (2,2,0): hold x2(l2), stream x1(l2)
        do_path<5, 5, 5, 1, false>(r2 + 128, r1 + 128, W + 9 * 32768 + w0,  w3t + 9 * 128, 0, acc, lds, lane);
    } else if (io == 1) {
        // (0,1,1): hold x1(l0), stream x2(l1)
        do_path<1, 3, 3, 3, true >(r1 + 0,   r2 + 32,  W + 1 * 32768 + w0,  w3t + 1 * 128, k, acc, lds, lane);
        // (1,0,1): hold x2(l0), stream x1(l1)
        do_path<1, 3, 1, 3, false>(r2 + 0,   r1 + 32,  W + 3 * 32768 + w0,  w3t + 3 * 128, k, acc, lds, lane);
        // (1,2,1): hold x1(l1), stream x2(l2)
        do_path<3, 5, 5, 3, true >(r1 + 32,  r2 + 128, W + 6 * 32768 + w0,  w3t + 6 * 128, k, acc, lds, lane);
        // (2,1,1): hold x2(l1), stream x1(l2)
        do_path<3, 5, 3, 3, false>(r2 + 32,  r1 + 128, W + 8 * 32768 + w0,  w3t + 8 * 128, k, acc, lds, lane);
    } else {
        // (0,2,2): hold x1(l0), stream x2(l2)
        do_path<1, 5, 5, 5, true >(r1 + 0,   r2 + 128, W + 2 * 32768 + w0,  w3t + 2 * 128, k, acc, lds, lane);
        // (1,1,2): hold x2(l1), stream x1(l1)
        do_path<3, 3, 3, 5, false>(r2 + 32,  r1 + 32,  W + 5 * 32768 + w0,  w3t + 5 * 128, k, acc, lds, lane);
        // (2,0,2): hold x2(l0), stream x1(l2)  [D2=1: x2 is l0]
        do_path<1, 5, 1, 5, false>(r2 + 0,   r1 + 128, W + 7 * 32768 + w0,  w3t + 7 * 128, k, acc, lds, lane);
        // (2,2,2): hold x2(l2), stream x1(l2)
        do_path<5, 5, 5, 5, false>(r2 + 128, r1 + 128, W + 10 * 32768 + w0, w3t + 10 * 128, k, acc, lds, lane);
    }

    // epilogue: alpha = sqrt((2lo+1)/fan_in)
    const float alpha = (io == 0) ? 0.018042196f : ((io == 1) ? 0.027063294f : 0.034938562f);
    const int off_o   = (io == 0) ? 0 : ((io == 1) ? 32 : 128);
    const int DOd     = (io == 0) ? 1 : ((io == 1) ? 3 : 5);
    float* orow = out + (size_t)z * 288 + off_o + k;
#pragma unroll
    for (int w = 0; w < 16; ++w) orow[(w0 + w) * DOd] = alpha * acc[w];
}

// ---------------- launch -----------------------------------------------------

extern "C" void kernel_launch(void* const* d_in, const int* in_sizes, int n_in,
                              void* d_out, int out_size, void* d_ws, size_t ws_size,
                              hipStream_t stream) {
    const float* x1 = (const float*)d_in[0];
    const float* x2 = (const float*)d_in[1];
    const float* W  = (const float*)d_in[2];
    float* out = (float*)d_out;

    wigner3j_setup<<<dim3(11), dim3(128), 0, stream>>>();
    tp_main<<<dim3(128, 9, 2), dim3(64), 0, stream>>>(x1, x2, W, out);
}